// Round 5
// baseline (4135.866 us; speedup 1.0000x reference)
//
#include <hip/hip_runtime.h>
#include <hip/hip_fp16.h>
#include <hip/hip_cooperative_groups.h>
#include <math.h>

namespace cg = cooperative_groups;

#define HID 16
#define BIN_SHIFT 7              // 128 nodes per bin
#define BIN_NODES 128
#define CAP 12288                // LDS packed-entry capacity (48KB); bins are ~6400 +/- 80

typedef int int4v __attribute__((ext_vector_type(4)));

// ---------------------------------------------------------------------------
// CSR build: count, prefix-sum, then 2-phase radix partition (dense writes).
// ---------------------------------------------------------------------------

__global__ void count_deg(const int* __restrict__ dst, int* __restrict__ cnt, int E) {
    int E4 = E >> 2;
    int t = blockIdx.x * blockDim.x + threadIdx.x;
    int stride = gridDim.x * blockDim.x;
    const int4v* dst4 = (const int4v*)dst;
    for (int q = t; q < E4; q += stride) {
        int4v d = __builtin_nontemporal_load(dst4 + q);
        atomicAdd(&cnt[d.x], 1);
        atomicAdd(&cnt[d.y], 1);
        atomicAdd(&cnt[d.z], 1);
        atomicAdd(&cnt[d.w], 1);
    }
    for (int e = (E4 << 2) + t; e < E; e += stride) atomicAdd(&cnt[dst[e]], 1);
}

__global__ void block_reduce(const int* __restrict__ cnt, int* __restrict__ bsum, int N) {
    int i = blockIdx.x * blockDim.x + threadIdx.x;
    int v = (i < N) ? cnt[i] : 0;
#pragma unroll
    for (int o = 1; o < 64; o <<= 1) v += __shfl_xor(v, o);
    __shared__ int ws[4];
    int lane = threadIdx.x & 63;
    int wid = threadIdx.x >> 6;
    if (lane == 0) ws[wid] = v;
    __syncthreads();
    if (threadIdx.x == 0) bsum[blockIdx.x] = ws[0] + ws[1] + ws[2] + ws[3];
}

__global__ void scan_bsums(int* __restrict__ bsum, int* __restrict__ row_ptr,
                           int nb, int N) {
    __shared__ int s[1024];
    int t = threadIdx.x;
    int v = (t < nb) ? bsum[t] : 0;
    s[t] = v;
    __syncthreads();
    for (int o = 1; o < 1024; o <<= 1) {
        int add = (t >= o) ? s[t - o] : 0;
        __syncthreads();
        s[t] += add;
        __syncthreads();
    }
    if (t < nb) bsum[t] = s[t] - v;            // exclusive
    if (t == 0) row_ptr[N] = s[1023];          // total == E
}

// scan cnt -> row_ptr, bin append-cursors (bincur[b] = row_ptr[b*128]), w9/dinv,
// and the fused encoder + head projection:
// y = h_K @ W3 + b3 is scalar and propagation is linear, so project BEFORE
// propagating: z0 = dinv * (relu-MLP(x) @ W3); APPNP recurrence keeps its form.
__global__ void finalize_encode(const int* __restrict__ cnt, const int* __restrict__ bsum,
                                int* __restrict__ row_ptr, int* __restrict__ bincur,
                                float* __restrict__ w9, float* __restrict__ dinv,
                                const float* __restrict__ x, const float* __restrict__ W1,
                                const float* __restrict__ b1, const float* __restrict__ W2,
                                const float* __restrict__ b2, const float* __restrict__ W3,
                                float* __restrict__ z0, int N) {
    __shared__ int s[256];
    int t = threadIdx.x;
    int i = blockIdx.x * blockDim.x + t;
    int c = (i < N) ? cnt[i] : 0;
    s[t] = c;
    __syncthreads();
    for (int o = 1; o < 256; o <<= 1) {
        int add = (t >= o) ? s[t - o] : 0;
        __syncthreads();
        s[t] += add;
        __syncthreads();
    }
    if (i >= N) return;
    int off = bsum[blockIdx.x] + s[t] - c;
    row_ptr[i] = off;
    if ((i & (BIN_NODES - 1)) == 0) bincur[i >> BIN_SHIFT] = off;
    float deg = (float)(c + 1);                 // +1 self-loop
    w9[i]   = 0.9f / deg;
    float dv = rsqrtf(deg);
    dinv[i] = dv;

    float xv = x[i];
    float h1[HID];
#pragma unroll
    for (int j = 0; j < HID; ++j) h1[j] = fmaxf(xv * W1[j] + b1[j], 0.0f);
    float zacc = 0.0f;
#pragma unroll
    for (int j = 0; j < HID; ++j) {
        float acc = b2[j];
#pragma unroll
        for (int q = 0; q < HID; ++q) acc += h1[q] * W2[q * HID + j];
        zacc += fmaxf(acc, 0.0f) * W3[j];
    }
    z0[i] = dv * zacc;
}

// Phase A: single pass over edges; append packed (d_local<<17 | src) into col
// at the bin's exact CSR offset range. Appends are dense per bin head -> L2
// write-combines by construction (vs the 8-pass range scatter's 13x write amp).
// src < 2^17 (N=100000) and d_local < 2^7 pack into 24 bits.
__global__ void bin_edges(const int* __restrict__ src, const int* __restrict__ dst,
                          int* __restrict__ bincur, int* __restrict__ colpk, int E) {
    int t = blockIdx.x * blockDim.x + threadIdx.x;
    int stride = gridDim.x * blockDim.x;
    int E4 = E >> 2;
    const int4v* d4 = (const int4v*)dst;
    const int4v* s4 = (const int4v*)src;
    for (int q = t; q < E4; q += stride) {
        int4v d = __builtin_nontemporal_load(d4 + q);
        int4v s = __builtin_nontemporal_load(s4 + q);
        int p;
        p = atomicAdd(&bincur[d.x >> BIN_SHIFT], 1);
        colpk[p] = ((d.x & (BIN_NODES - 1)) << 17) | s.x;
        p = atomicAdd(&bincur[d.y >> BIN_SHIFT], 1);
        colpk[p] = ((d.y & (BIN_NODES - 1)) << 17) | s.y;
        p = atomicAdd(&bincur[d.z >> BIN_SHIFT], 1);
        colpk[p] = ((d.z & (BIN_NODES - 1)) << 17) | s.z;
        p = atomicAdd(&bincur[d.w >> BIN_SHIFT], 1);
        colpk[p] = ((d.w & (BIN_NODES - 1)) << 17) | s.w;
    }
    for (int e = (E4 << 2) + t; e < E; e += stride) {
        int d = dst[e];
        int p = atomicAdd(&bincur[d >> BIN_SHIFT], 1);
        colpk[p] = ((d & (BIN_NODES - 1)) << 17) | src[e];
    }
}

// Phase B: one block per bin. Snapshot the bin's packed region into LDS, then
// scatter src ids to final CSR positions via LDS cursors. All writes land in a
// block-private ~25KB window -> full line combining. Fallback (statistically
// unreachable: bins are 6400 +/- 80, CAP=12288) rescans the raw edge list.
__global__ void scatter_bins(const int* __restrict__ row_ptr, int* __restrict__ col,
                             const int* __restrict__ src, const int* __restrict__ dst,
                             int E, int N) {
    __shared__ int cache[CAP];
    __shared__ int cur[BIN_NODES];
    int b = blockIdx.x;
    int node0 = b << BIN_SHIFT;
    int nn = min(BIN_NODES, N - node0);
    int lo = row_ptr[node0];
    int hi = row_ptr[node0 + nn];
    int sz = hi - lo;
    for (int i = threadIdx.x; i < nn; i += blockDim.x) cur[i] = row_ptr[node0 + i];
    if (sz <= CAP) {
        for (int k = threadIdx.x; k < sz; k += blockDim.x)
            cache[k] = __builtin_nontemporal_load(col + lo + k);
        __syncthreads();
        for (int k = threadIdx.x; k < sz; k += blockDim.x) {
            int p = cache[k];
            int pos = atomicAdd(&cur[p >> 17], 1);
            col[pos] = p & 0x1FFFF;
        }
    } else {
        __syncthreads();
        for (int e = threadIdx.x; e < E; e += blockDim.x) {
            int d = dst[e];
            if ((d >> BIN_SHIFT) == b) {
                int pos = atomicAdd(&cur[d & (BIN_NODES - 1)], 1);
                col[pos] = src[e];
            }
        }
    }
}

// ---------------------------------------------------------------------------
// All 10 APPNP rounds + head in ONE cooperative kernel (grid.sync between
// rounds) — removes 10 dispatch/drain boundaries. z fp32 400KB, L2-resident.
// ---------------------------------------------------------------------------
__device__ __forceinline__ float row_sum(const float* __restrict__ zin,
                                         const int* __restrict__ col,
                                         int s, int e, int j) {
    float acc = 0.0f, acc2 = 0.0f;
    int k = s + j;
    for (; k + 4 < e; k += 8) {
        int c0 = __builtin_nontemporal_load(col + k);
        int c1 = __builtin_nontemporal_load(col + k + 4);
        acc  += zin[c0];
        acc2 += zin[c1];
    }
    if (k < e) acc += zin[__builtin_nontemporal_load(col + k)];
    acc += acc2;
    acc += __shfl_xor(acc, 1, 4);
    acc += __shfl_xor(acc, 2, 4);
    return acc;
}

__global__ void prop_all(const float* __restrict__ z0, float* __restrict__ zA,
                         float* __restrict__ zB,
                         const int* __restrict__ row_ptr, const int* __restrict__ col,
                         const float* __restrict__ w9, const float* __restrict__ dinv,
                         const float* __restrict__ b3, float* __restrict__ y, int N) {
    cg::grid_group grid = cg::this_grid();
    int tid = blockIdx.x * blockDim.x + threadIdx.x;
    int vstride = (gridDim.x * blockDim.x) >> 2;
    int j = tid & 3;
    const float* zin = z0;
    float* zout = zA;
    for (int round = 0; round < 10; ++round) {
        bool last = (round == 9);
        for (int v = tid >> 2; v < N; v += vstride) {
            int s = row_ptr[v];
            int e = row_ptr[v + 1];
            float acc = row_sum(zin, col, s, e, j);
            if (j == 0) {
                float zf = w9[v] * (acc + zin[v]) + 0.1f * z0[v];
                if (last) y[v] = zf / dinv[v] + b3[0];
                else      zout[v] = zf;
            }
        }
        if (!last) {
            __threadfence();
            grid.sync();
            const float* t = zin;
            zin  = zout;
            zout = (t == z0) ? zB : (float*)t;
        }
    }
}

extern "C" void kernel_launch(void* const* d_in, const int* in_sizes, int n_in,
                              void* d_out, int out_size, void* d_ws, size_t ws_size,
                              hipStream_t stream) {
    const float* x  = (const float*)d_in[0];
    const int* edge = (const int*)d_in[1];
    const float* W1 = (const float*)d_in[2];
    const float* b1 = (const float*)d_in[3];
    const float* W2 = (const float*)d_in[4];
    const float* b2 = (const float*)d_in[5];
    const float* W3 = (const float*)d_in[6];
    const float* b3 = (const float*)d_in[7];
    float* y = (float*)d_out;

    const int N = in_sizes[0];       // 100000
    const int E = in_sizes[1] / 2;   // 5000000
    const int* src = edge;
    const int* dst = edge + E;
    const int NBINS = (N + BIN_NODES - 1) >> BIN_SHIFT;   // 782

    char* ws = (char*)d_ws;
    size_t off = 0;
    auto alloc = [&](size_t bytes) -> void* {
        void* p = ws + off;
        off += (bytes + 255) & ~(size_t)255;
        return p;
    };

    int*    cnt     = (int*)   alloc((size_t)N * 4);
    int*    row_ptr = (int*)   alloc((size_t)(N + 1) * 4);
    int*    col     = (int*)   alloc((size_t)E * 4);
    float*  w9      = (float*) alloc((size_t)N * 4);
    float*  dinv    = (float*) alloc((size_t)N * 4);
    float*  z0f     = (float*) alloc((size_t)N * 4);
    float*  zA      = (float*) alloc((size_t)N * 4);
    float*  zB      = (float*) alloc((size_t)N * 4);
    int*    bsum    = (int*)   alloc(1024 * 4);
    int*    bincur  = (int*)   alloc((size_t)NBINS * 4);

    const int nb = (N + 255) / 256;   // 391 <= 1024

    hipMemsetAsync(cnt, 0, (size_t)N * 4, stream);

    count_deg<<<2048, 256, 0, stream>>>(dst, cnt, E);
    block_reduce<<<nb, 256, 0, stream>>>(cnt, bsum, N);
    scan_bsums<<<1, 1024, 0, stream>>>(bsum, row_ptr, nb, N);
    finalize_encode<<<nb, 256, 0, stream>>>(cnt, bsum, row_ptr, bincur, w9, dinv,
                                            x, W1, b1, W2, b2, W3, z0f, N);

    bin_edges<<<2048, 256, 0, stream>>>(src, dst, bincur, col, E);
    scatter_bins<<<NBINS, 256, 0, stream>>>(row_ptr, col, src, dst, E, N);

    // cooperative launch: 1024 blocks x 256 = 4 blocks/CU (16 waves/CU),
    // comfortably co-resident (VGPR-light, no LDS).
    int Nc = N;
    void* args[] = {(void*)&z0f, (void*)&zA, (void*)&zB, (void*)&row_ptr,
                    (void*)&col, (void*)&w9, (void*)&dinv, (void*)&b3, (void*)&y,
                    (void*)&Nc};
    hipLaunchCooperativeKernel((void*)prop_all, dim3(1024), dim3(256), args, 0, stream);
}

// Round 6
// 797.775 us; speedup vs baseline: 5.1842x; 5.1842x over previous
//
#include <hip/hip_runtime.h>
#include <hip/hip_fp16.h>
#include <math.h>

#define HID 16
#define RANGES 8

typedef int int4v __attribute__((ext_vector_type(4)));

// ---------------------------------------------------------------------------
// CSR build: count in-degrees, hierarchical prefix-sum, range-filtered scatter
// ---------------------------------------------------------------------------

// int4-vectorized degree count. CACHED loads (not NT): this pass warms L3 with
// dst for fill_csr's 8 re-reads.
__global__ void count_deg(const int* __restrict__ dst, int* __restrict__ cnt, int E) {
    int E4 = E >> 2;
    int t = blockIdx.x * blockDim.x + threadIdx.x;
    int stride = gridDim.x * blockDim.x;
    const int4v* dst4 = (const int4v*)dst;
    for (int q = t; q < E4; q += stride) {
        int4v d = dst4[q];
        atomicAdd(&cnt[d.x], 1);
        atomicAdd(&cnt[d.y], 1);
        atomicAdd(&cnt[d.z], 1);
        atomicAdd(&cnt[d.w], 1);
    }
    for (int e = (E4 << 2) + t; e < E; e += stride) atomicAdd(&cnt[dst[e]], 1);
}

__global__ void block_reduce(const int* __restrict__ cnt, int* __restrict__ bsum, int N) {
    int i = blockIdx.x * blockDim.x + threadIdx.x;
    int v = (i < N) ? cnt[i] : 0;
#pragma unroll
    for (int o = 1; o < 64; o <<= 1) v += __shfl_xor(v, o);
    __shared__ int ws[4];
    int lane = threadIdx.x & 63;
    int wid = threadIdx.x >> 6;
    if (lane == 0) ws[wid] = v;
    __syncthreads();
    if (threadIdx.x == 0) bsum[blockIdx.x] = ws[0] + ws[1] + ws[2] + ws[3];
}

__global__ void scan_bsums(int* __restrict__ bsum, int* __restrict__ row_ptr,
                           int nb, int N) {
    __shared__ int s[1024];
    int t = threadIdx.x;
    int v = (t < nb) ? bsum[t] : 0;
    s[t] = v;
    __syncthreads();
    for (int o = 1; o < 1024; o <<= 1) {
        int add = (t >= o) ? s[t - o] : 0;
        __syncthreads();
        s[t] += add;
        __syncthreads();
    }
    if (t < nb) bsum[t] = s[t] - v;            // exclusive
    if (t == 0) row_ptr[N] = s[1023];          // total == E
}

// Stage 3 + encoder fused: scan cnt -> row_ptr/cursor/w9, compute dinv, and
// immediately run the per-node MLP encoder + head projection.
// KEY: y = h_K @ W3 + b3 is scalar per node and propagation is linear, so we
// project h0 @ W3 BEFORE propagating: z0 = dinv * (relu-MLP(x) @ W3).
// The APPNP recurrence on z is identical in form (HID=1).
__global__ void finalize_encode(const int* __restrict__ cnt, const int* __restrict__ bsum,
                                int* __restrict__ row_ptr, int* __restrict__ cursor,
                                float* __restrict__ w9, float* __restrict__ dinv,
                                const float* __restrict__ x, const float* __restrict__ W1,
                                const float* __restrict__ b1, const float* __restrict__ W2,
                                const float* __restrict__ b2, const float* __restrict__ W3,
                                float* __restrict__ z0, int N) {
    __shared__ int s[256];
    int t = threadIdx.x;
    int i = blockIdx.x * blockDim.x + t;
    int c = (i < N) ? cnt[i] : 0;
    s[t] = c;
    __syncthreads();
    for (int o = 1; o < 256; o <<= 1) {
        int add = (t >= o) ? s[t - o] : 0;
        __syncthreads();
        s[t] += add;
        __syncthreads();
    }
    if (i >= N) return;
    int off = bsum[blockIdx.x] + s[t] - c;
    row_ptr[i] = off;
    cursor[i]  = off;
    float deg = (float)(c + 1);                 // +1 self-loop
    w9[i]   = 0.9f / deg;
    float dv = rsqrtf(deg);
    dinv[i] = dv;

    // ---- encoder + head: z0 = dinv * (relu(relu(x*W1+b1)@W2+b2) @ W3) ----
    float xv = x[i];
    float h1[HID];
#pragma unroll
    for (int j = 0; j < HID; ++j) h1[j] = fmaxf(xv * W1[j] + b1[j], 0.0f);
    float zacc = 0.0f;
#pragma unroll
    for (int j = 0; j < HID; ++j) {
        float acc = b2[j];
#pragma unroll
        for (int q = 0; q < HID; ++q) acc += h1[q] * W2[q * HID + j];
        zacc += fmaxf(acc, 0.0f) * W3[j];
    }
    z0[i] = dv * zacc;
}

// Range-filtered scatter: blockIdx%8 selects a dst range; round-robin
// workgroup->XCD dispatch keeps each col window mostly in one XCD's L2.
// Cached (non-NT) loads: dst/src stay L3-resident across the 8 passes.
// (R4 measured: NT loads here RAISE fetch 156->213MB and cost +26us.)
__global__ void fill_csr(const int* __restrict__ src, const int* __restrict__ dst,
                         int* __restrict__ cursor, int* __restrict__ col,
                         int E, int range_step, int N) {
    int r = blockIdx.x & (RANGES - 1);
    int chunk = blockIdx.x >> 3;
    int nchunks = gridDim.x >> 3;
    int lo = r * range_step;
    int hi = min(lo + range_step, N);
    int stride = nchunks * blockDim.x;
    for (int e = chunk * blockDim.x + threadIdx.x; e < E; e += stride) {
        int d = dst[e];
        if (d >= lo && d < hi) {
            int sv = src[e];
            int p = atomicAdd(&cursor[d], 1);
            col[p] = sv;
        }
    }
}

// ---------------------------------------------------------------------------
// Scalar APPNP round: z_out[v] = w9[v]*(sum_in z[src] + z[v]) + 0.1*z0[v]
// z state fp32, 400KB, L2-resident. col loads are CACHED (not NT!): col is
// read by all 10 rounds — NT was forcing a 20MB HBM re-stream every round
// (~60us/round); cached, rounds 2-10 serve col from L3.
// 4 lanes/node; 2-deep accumulator unroll for gather ILP; 4-lane shfl reduce.
// ---------------------------------------------------------------------------
__device__ __forceinline__ float row_sum(const float* __restrict__ zin,
                                         const int* __restrict__ col,
                                         int s, int e, int j) {
    float acc = 0.0f, acc2 = 0.0f;
    int k = s + j;
    for (; k + 4 < e; k += 8) {
        int c0 = col[k];
        int c1 = col[k + 4];
        acc  += zin[c0];
        acc2 += zin[c1];
    }
    if (k < e) acc += zin[col[k]];
    acc += acc2;
    acc += __shfl_xor(acc, 1, 4);
    acc += __shfl_xor(acc, 2, 4);
    return acc;
}

__global__ void prop_scalar(const float* __restrict__ zin, const float* __restrict__ z0,
                            const int* __restrict__ row_ptr, const int* __restrict__ col,
                            const float* __restrict__ w9, float* __restrict__ zout, int N) {
    int gid = blockIdx.x * blockDim.x + threadIdx.x;
    int v = gid >> 2;
    if (v >= N) return;
    int j = threadIdx.x & 3;
    int s = row_ptr[v];
    int e = row_ptr[v + 1];
    float acc = row_sum(zin, col, s, e, j);
    if (j == 0) zout[v] = w9[v] * (acc + zin[v]) + 0.1f * z0[v];
}

// Final round fused with the head recovery: y = z_final / dinv + b3.
__global__ void prop_last(const float* __restrict__ zin, const float* __restrict__ z0,
                          const int* __restrict__ row_ptr, const int* __restrict__ col,
                          const float* __restrict__ w9, const float* __restrict__ dinv,
                          const float* __restrict__ b3, float* __restrict__ y, int N) {
    int gid = blockIdx.x * blockDim.x + threadIdx.x;
    int v = gid >> 2;
    if (v >= N) return;
    int j = threadIdx.x & 3;
    int s = row_ptr[v];
    int e = row_ptr[v + 1];
    float acc = row_sum(zin, col, s, e, j);
    if (j == 0) {
        float zf = w9[v] * (acc + zin[v]) + 0.1f * z0[v];
        y[v] = zf / dinv[v] + b3[0];
    }
}

extern "C" void kernel_launch(void* const* d_in, const int* in_sizes, int n_in,
                              void* d_out, int out_size, void* d_ws, size_t ws_size,
                              hipStream_t stream) {
    const float* x  = (const float*)d_in[0];
    const int* edge = (const int*)d_in[1];
    const float* W1 = (const float*)d_in[2];
    const float* b1 = (const float*)d_in[3];
    const float* W2 = (const float*)d_in[4];
    const float* b2 = (const float*)d_in[5];
    const float* W3 = (const float*)d_in[6];
    const float* b3 = (const float*)d_in[7];
    float* y = (float*)d_out;

    const int N = in_sizes[0];       // 100000
    const int E = in_sizes[1] / 2;   // 5000000
    const int* src = edge;
    const int* dst = edge + E;

    char* ws = (char*)d_ws;
    size_t off = 0;
    auto alloc = [&](size_t bytes) -> void* {
        void* p = ws + off;
        off += (bytes + 255) & ~(size_t)255;
        return p;
    };

    int*    cnt     = (int*)   alloc((size_t)N * 4);
    int*    row_ptr = (int*)   alloc((size_t)(N + 1) * 4);
    int*    cursor  = (int*)   alloc((size_t)N * 4);
    int*    col     = (int*)   alloc((size_t)E * 4);
    float*  w9      = (float*) alloc((size_t)N * 4);
    float*  dinv    = (float*) alloc((size_t)N * 4);
    float*  z0f     = (float*) alloc((size_t)N * 4);
    float*  zA      = (float*) alloc((size_t)N * 4);
    float*  zB      = (float*) alloc((size_t)N * 4);
    int*    bsum    = (int*)   alloc(1024 * 4);

    const int nb = (N + 255) / 256;   // 391 <= 1024

    hipMemsetAsync(cnt, 0, (size_t)N * 4, stream);

    count_deg<<<2048, 256, 0, stream>>>(dst, cnt, E);
    block_reduce<<<nb, 256, 0, stream>>>(cnt, bsum, N);
    scan_bsums<<<1, 1024, 0, stream>>>(bsum, row_ptr, nb, N);
    finalize_encode<<<nb, 256, 0, stream>>>(cnt, bsum, row_ptr, cursor, w9, dinv,
                                            x, W1, b1, W2, b2, W3, z0f, N);

    int range_step = (N + RANGES - 1) / RANGES;
    fill_csr<<<2048, 256, 0, stream>>>(src, dst, cursor, col, E, range_step, N);

    const float* zin = z0f;           // round 0 state IS z0
    float* zout = zA;
    long long total = (long long)N * 4;        // 4 lanes per node
    int pgrid = (int)((total + 255) / 256);
    for (int k = 0; k < 9; ++k) {
        prop_scalar<<<pgrid, 256, 0, stream>>>(zin, z0f, row_ptr, col, w9, zout, N);
        zin = zout;
        zout = (zout == zA) ? zB : zA;
    }
    prop_last<<<pgrid, 256, 0, stream>>>(zin, z0f, row_ptr, col, w9, dinv, b3, y, N);
}